// Round 1
// baseline (1374.677 us; speedup 1.0000x reference)
//
#include <hip/hip_runtime.h>
#include <hip/hip_bf16.h>

#define GN 16384
#define GD 128

typedef __attribute__((ext_vector_type(8))) short short8;
typedef __attribute__((ext_vector_type(4))) float floatx4;
typedef __attribute__((ext_vector_type(4))) int intx4;

static __device__ __forceinline__ unsigned short f32_to_bf16(float f) {
  unsigned u = __builtin_bit_cast(unsigned, f);
  unsigned r = u + 0x7FFFu + ((u >> 16) & 1u);   // RNE (inputs are finite/normal)
  return (unsigned short)(r >> 16);
}

// Kernel 1: out <- x (identity term, also un-poisons d_out); xT[d][j] <- bf16(x[j][d])
__global__ __launch_bounds__(256) void prep_kernel(const float* __restrict__ x,
                                                   float* __restrict__ out,
                                                   unsigned short* __restrict__ xT) {
  __shared__ unsigned short t[GD][66];  // +2 pad keeps 4B alignment & kills bank conflicts
  const int tid = threadIdx.x;
  const int j0 = blockIdx.x * 64;
  for (int i = tid; i < 64 * GD; i += 256) {
    int j = i >> 7, d = i & (GD - 1);
    float v = x[(size_t)(j0 + j) * GD + d];
    out[(size_t)(j0 + j) * GD + d] = v;
    t[d][j] = f32_to_bf16(v);
  }
  __syncthreads();
  for (int i = tid; i < GD * 32; i += 256) {
    int d = i >> 5, jp = i & 31;
    unsigned lo = t[d][2 * jp], hi = t[d][2 * jp + 1];
    *reinterpret_cast<unsigned*>(xT + (size_t)d * GN + j0 + 2 * jp) = lo | (hi << 16);
  }
}

// Kernel 2: out += adj @ x   (bf16 MFMA, fp32 accumulate, atomic k-split epilogue)
// Block: 256 thr (4 waves). BM=128 rows x BN=128 (full D). BK=32. KSPLIT=4.
// wave w owns rows [bx*128 + w*32, +32) : 2 row-tiles x 8 col-tiles of 16x16x32.
__global__ __launch_bounds__(256, 2) void gemm_kernel(const int* __restrict__ adj,
                                                      const unsigned short* __restrict__ xT,
                                                      float* __restrict__ out) {
  __shared__ unsigned short bbuf[2][32 * GD];  // 2 x 8KB, layout [n][k] rows of 64B
  const int tid = threadIdx.x;
  const int wave = tid >> 6;
  const int lane = tid & 63;
  const int q = lane >> 4;   // 0..3
  const int m = lane & 15;   // 0..15
  const int rbase = blockIdx.x * 128 + wave * 32;
  const int kbase = blockIdx.y * 4096;

  const int* arow0 = adj + (size_t)(rbase + m) * GN;
  const int* arow1 = adj + (size_t)(rbase + 16 + m) * GN;

  // B staging: chunk c (16B) -> lds byte c*16 ; source row n=c>>2, k-sub=(c&3)*8
  const int c1 = tid, c2 = tid + 256;
  const unsigned short* g1 = xT + (size_t)(c1 >> 2) * GN + (c1 & 3) * 8;
  const unsigned short* g2 = xT + (size_t)(c2 >> 2) * GN + (c2 & 3) * 8;
  unsigned short* l1 = &bbuf[0][0] + c1 * 8;
  unsigned short* l2 = &bbuf[0][0] + c2 * 8;

  floatx4 acc[2][8];
#pragma unroll
  for (int t = 0; t < 2; ++t)
#pragma unroll
    for (int c = 0; c < 8; ++c) acc[t][c] = (floatx4){0.f, 0.f, 0.f, 0.f};

#define STAGE_B(k0, buf)                                                               \
  do {                                                                                 \
    __builtin_amdgcn_global_load_lds(                                                  \
        (const __attribute__((address_space(1))) unsigned int*)(g1 + (k0)),            \
        (__attribute__((address_space(3))) unsigned int*)(l1 + (buf) * (32 * GD)),     \
        16, 0, 0);                                                                     \
    __builtin_amdgcn_global_load_lds(                                                  \
        (const __attribute__((address_space(1))) unsigned int*)(g2 + (k0)),            \
        (__attribute__((address_space(3))) unsigned int*)(l2 + (buf) * (32 * GD)),     \
        16, 0, 0);                                                                     \
  } while (0)

#define LOAD_ADJ(k0, r)                                                                \
  do {                                                                                 \
    const int kk_ = (k0) + q * 8;                                                      \
    r[0] = *(const intx4*)(arow0 + kk_);                                               \
    r[1] = *(const intx4*)(arow0 + kk_ + 4);                                           \
    r[2] = *(const intx4*)(arow1 + kk_);                                               \
    r[3] = *(const intx4*)(arow1 + kk_ + 4);                                           \
  } while (0)

  intx4 cur[4], nxt[4];
  STAGE_B(kbase, 0);
  LOAD_ADJ(kbase, cur);

  for (int i = 0; i < 128; ++i) {
    const int buf = i & 1;
    __syncthreads();  // drains staging+adj loads issued last iter (vmcnt before barrier)

    const int knext = kbase + ((i + 1) & 127) * 32;  // wraps on last iter (unused, in-bounds)
    STAGE_B(knext, buf ^ 1);
    LOAD_ADJ(knext, nxt);

    // B fragments: lane holds B[k=q*8+j][n= c*16+m] = xT row n, 8 consecutive k -> b128
    short8 bf[8];
    const unsigned short* bb = &bbuf[buf][0] + m * 32 + q * 8;
#pragma unroll
    for (int c = 0; c < 8; ++c) bf[c] = *(const short8*)(bb + c * 512);

    // adj int 0/1 -> bf16 0x0000/0x3F80, two elements per dword
    intx4 p0, p1;
    p0.x = (cur[0].x | (cur[0].y << 16)) * 0x3F80;
    p0.y = (cur[0].z | (cur[0].w << 16)) * 0x3F80;
    p0.z = (cur[1].x | (cur[1].y << 16)) * 0x3F80;
    p0.w = (cur[1].z | (cur[1].w << 16)) * 0x3F80;
    p1.x = (cur[2].x | (cur[2].y << 16)) * 0x3F80;
    p1.y = (cur[2].z | (cur[2].w << 16)) * 0x3F80;
    p1.z = (cur[3].x | (cur[3].y << 16)) * 0x3F80;
    p1.w = (cur[3].z | (cur[3].w << 16)) * 0x3F80;
    short8 af0 = __builtin_bit_cast(short8, p0);
    short8 af1 = __builtin_bit_cast(short8, p1);

#pragma unroll
    for (int c = 0; c < 8; ++c) {
      acc[0][c] = __builtin_amdgcn_mfma_f32_16x16x32_bf16(af0, bf[c], acc[0][c], 0, 0, 0);
      acc[1][c] = __builtin_amdgcn_mfma_f32_16x16x32_bf16(af1, bf[c], acc[1][c], 0, 0, 0);
    }

#pragma unroll
    for (int u = 0; u < 4; ++u) cur[u] = nxt[u];
  }

  // Epilogue: C/D layout col=lane&15, row=q*4+reg. k-split partials -> atomicAdd.
  const size_t obase = (size_t)rbase * GD;
#pragma unroll
  for (int t = 0; t < 2; ++t)
#pragma unroll
    for (int c = 0; c < 8; ++c)
#pragma unroll
      for (int r = 0; r < 4; ++r) {
        int row = t * 16 + q * 4 + r;
        int col = c * 16 + m;
        atomicAdd(out + obase + (size_t)row * GD + col, acc[t][c][r]);
      }
}

extern "C" void kernel_launch(void* const* d_in, const int* in_sizes, int n_in,
                              void* d_out, int out_size, void* d_ws, size_t ws_size,
                              hipStream_t stream) {
  const float* x = (const float*)d_in[0];
  const int* adj = (const int*)d_in[1];
  float* out = (float*)d_out;
  unsigned short* xT = (unsigned short*)d_ws;  // 16384*128 bf16 = 4 MiB

  prep_kernel<<<GN / 64, 256, 0, stream>>>(x, out, xT);
  gemm_kernel<<<dim3(GN / 128, 4), 256, 0, stream>>>(adj, xT, out);
}